// Round 1
// baseline (2759.085 us; speedup 1.0000x reference)
//
#include <hip/hip_runtime.h>
#include <hip/hip_bf16.h>
#include <math.h>

// Problem dims (DAGNN_14594298872388)
#define NN     100000   // nodes
#define INDIM  500
#define HID    256
#define NCLASS 50
#define KHOPS  10

static inline size_t roundup256(size_t x) { return (x + 255) & ~(size_t)255; }

// ---------------------------------------------------------------------------
// zero int arrays (deg counters + fill counters)
// ---------------------------------------------------------------------------
__global__ void dagnn_zero2(int* __restrict__ a, int* __restrict__ b, int n) {
    int i = blockIdx.x * blockDim.x + threadIdx.x;
    if (i < n) { a[i] = 0; b[i] = 0; }
}

// ---------------------------------------------------------------------------
// in-degree count (includes self loops)
// ---------------------------------------------------------------------------
__global__ void dagnn_deg(const int* __restrict__ dst, int* __restrict__ degi, int E) {
    int e = blockIdx.x * blockDim.x + threadIdx.x;
    if (e < E) atomicAdd(&degi[dst[e]], 1);
}

__global__ void dagnn_norm(const int* __restrict__ degi, float* __restrict__ nrm, int n) {
    int i = blockIdx.x * blockDim.x + threadIdx.x;
    if (i < n) nrm[i] = rsqrtf((float)degi[i]);   // deg >= 1 (self loop)
}

// ---------------------------------------------------------------------------
// exclusive scan of degi -> rowptr[0..n], single block of 1024 threads
// ---------------------------------------------------------------------------
__global__ void dagnn_scan(const int* __restrict__ degi, int* __restrict__ rowptr, int n) {
    __shared__ int wsum[16];
    __shared__ int carry_s;
    const int tid  = threadIdx.x;        // 1024
    const int lane = tid & 63;
    const int wid  = tid >> 6;
    if (tid == 0) carry_s = 0;
    __syncthreads();
    for (int base = 0; base < n; base += 4096) {
        int i0 = base + tid * 4;
        int v0 = (i0 + 0 < n) ? degi[i0 + 0] : 0;
        int v1 = (i0 + 1 < n) ? degi[i0 + 1] : 0;
        int v2 = (i0 + 2 < n) ? degi[i0 + 2] : 0;
        int v3 = (i0 + 3 < n) ? degi[i0 + 3] : 0;
        int tsum = v0 + v1 + v2 + v3;
        // inclusive wave scan of tsum
        int x = tsum;
        #pragma unroll
        for (int off = 1; off < 64; off <<= 1) {
            int t = __shfl_up(x, off);
            if (lane >= off) x += t;
        }
        if (lane == 63) wsum[wid] = x;
        __syncthreads();
        if (tid == 0) {
            int run = carry_s;
            #pragma unroll
            for (int w = 0; w < 16; ++w) { int t = wsum[w]; wsum[w] = run; run += t; }
            carry_s = run;
        }
        __syncthreads();
        int texcl = wsum[wid] + (x - tsum);
        if (i0 + 0 < n) rowptr[i0 + 0] = texcl;
        if (i0 + 1 < n) rowptr[i0 + 1] = texcl + v0;
        if (i0 + 2 < n) rowptr[i0 + 2] = texcl + v0 + v1;
        if (i0 + 3 < n) rowptr[i0 + 3] = texcl + v0 + v1 + v2;
        __syncthreads();   // wsum reused next chunk
    }
    if (tid == 0) rowptr[n] = carry_s;
}

// ---------------------------------------------------------------------------
// CSR fill: colidx[rowptr[d] + slot] = src
// ---------------------------------------------------------------------------
__global__ void dagnn_fill(const int* __restrict__ src, const int* __restrict__ dst,
                           const int* __restrict__ rowptr, int* __restrict__ fillc,
                           int* __restrict__ colidx, int E) {
    int e = blockIdx.x * blockDim.x + threadIdx.x;
    if (e >= E) return;
    int d = dst[e];
    int pos = rowptr[d] + atomicAdd(&fillc[d], 1);
    colidx[pos] = src[e];
}

// ---------------------------------------------------------------------------
// GEMM1: hid = relu(feats @ W1 + b1)   [M,500] x [500,256]
// fp32 classic tile: 128x128 block, 8x8 per thread, BK=16
// ---------------------------------------------------------------------------
#define BM 128
#define BN 128
#define BK 16
__global__ __launch_bounds__(256) void dagnn_gemm1(
        const float* __restrict__ A, const float* __restrict__ B,
        const float* __restrict__ bias, float* __restrict__ C, int M) {
    __shared__ float As[BK][BM + 4];
    __shared__ float Bs[BK][BN];
    const int tid = threadIdx.x;
    const int tx = tid & 15;
    const int ty = tid >> 4;
    const int row0 = blockIdx.x * BM;
    const int col0 = blockIdx.y * BN;

    float acc[8][8];
    #pragma unroll
    for (int i = 0; i < 8; ++i)
        #pragma unroll
        for (int j = 0; j < 8; ++j) acc[i][j] = 0.f;

    for (int k0 = 0; k0 < INDIM; k0 += BK) {
        // load A tile (BM x BK), transposed into As[k][m]
        #pragma unroll
        for (int i = 0; i < 8; ++i) {
            int idx = tid + i * 256;       // 0..2047
            int m  = idx >> 4;
            int kk = idx & 15;
            int gm = row0 + m;
            int gk = k0 + kk;
            float v = 0.f;
            if (gm < M && gk < INDIM) v = A[(size_t)gm * INDIM + gk];
            As[kk][m] = v;
        }
        // load B tile (BK x BN)
        #pragma unroll
        for (int i = 0; i < 8; ++i) {
            int idx = tid + i * 256;
            int n  = idx & 127;
            int kk = idx >> 7;
            int gk = k0 + kk;
            float v = 0.f;
            if (gk < INDIM) v = B[(size_t)gk * HID + col0 + n];
            Bs[kk][n] = v;
        }
        __syncthreads();
        #pragma unroll
        for (int kk = 0; kk < BK; ++kk) {
            float a[8], b[8];
            #pragma unroll
            for (int i = 0; i < 8; ++i) a[i] = As[kk][ty * 8 + i];
            #pragma unroll
            for (int j = 0; j < 8; ++j) b[j] = Bs[kk][tx * 8 + j];
            #pragma unroll
            for (int i = 0; i < 8; ++i)
                #pragma unroll
                for (int j = 0; j < 8; ++j) acc[i][j] += a[i] * b[j];
        }
        __syncthreads();
    }

    float bv[8];
    #pragma unroll
    for (int j = 0; j < 8; ++j) bv[j] = bias[col0 + tx * 8 + j];
    #pragma unroll
    for (int i = 0; i < 8; ++i) {
        int gm = row0 + ty * 8 + i;
        if (gm >= M) continue;
        float* crow = C + (size_t)gm * HID + col0 + tx * 8;
        #pragma unroll
        for (int j = 0; j < 8; ++j) {
            float v = acc[i][j] + bv[j];
            crow[j] = v > 0.f ? v : 0.f;
        }
    }
}

// ---------------------------------------------------------------------------
// GEMM2 + epilogue: x = hid @ W2 + b2 ; h0 = x ; out = sigmoid(x . s) * x
// block = 256 threads = 4 waves; each wave handles 16 rows, lanes = channels
// ---------------------------------------------------------------------------
__global__ __launch_bounds__(256) void dagnn_mlp2(
        const float* __restrict__ hid, const float* __restrict__ W2,
        const float* __restrict__ b2, const float* __restrict__ svec,
        float* __restrict__ h0, float* __restrict__ out, int M) {
    __shared__ float sw2[HID * NCLASS];   // 51.2 KB
    __shared__ float sb2[64];
    __shared__ float ss[64];
    const int tid = threadIdx.x;
    for (int i = tid; i < HID * NCLASS; i += 256) sw2[i] = W2[i];
    if (tid < 64) {
        sb2[tid] = (tid < NCLASS) ? b2[tid] : 0.f;
        ss[tid]  = (tid < NCLASS) ? svec[tid] : 0.f;
    }
    __syncthreads();

    const int c    = tid & 63;
    const int rg   = tid >> 6;                 // wave id 0..3
    const int row0 = blockIdx.x * 64 + rg * 16;
    const bool act = (c < NCLASS);

    int roff[16];
    #pragma unroll
    for (int r = 0; r < 16; ++r) {
        int row = row0 + r;
        if (row >= M) row = M - 1;             // clamp (stores guarded)
        roff[r] = row * HID;
    }

    float acc[16];
    #pragma unroll
    for (int r = 0; r < 16; ++r) acc[r] = 0.f;

    for (int k = 0; k < HID; ++k) {
        float w = act ? sw2[k * NCLASS + c] : 0.f;
        #pragma unroll
        for (int r = 0; r < 16; ++r)
            acc[r] += hid[(size_t)roff[r] + k] * w;   // wave-uniform broadcast load
    }

    #pragma unroll
    for (int r = 0; r < 16; ++r) {
        int row = row0 + r;
        float v = acc[r] + sb2[c];
        float p = act ? v * ss[c] : 0.f;
        #pragma unroll
        for (int off = 32; off; off >>= 1) p += __shfl_xor(p, off);
        float S = 1.f / (1.f + __expf(-p));
        if (act && row < M) {
            h0[(size_t)row * NCLASS + c]  = v;
            out[(size_t)row * NCLASS + c] = S * v;
        }
    }
}

// ---------------------------------------------------------------------------
// propagation hop: h_out[d] = norm[d] * sum_{s in N(d)} h[s]*norm[s]
// + online epilogue: out[d] += sigmoid(h_out[d] . s) * h_out[d]
// one wave per dst row; lanes = channels
// ---------------------------------------------------------------------------
__global__ __launch_bounds__(256) void dagnn_prop(
        const float* __restrict__ h, const float* __restrict__ nrm,
        const int* __restrict__ rowptr, const int* __restrict__ colidx,
        const float* __restrict__ svec, float* __restrict__ hnext,
        float* __restrict__ out, int M) {
    const int lane = threadIdx.x & 63;
    const int wid  = threadIdx.x >> 6;
    const int d    = blockIdx.x * 4 + wid;
    if (d >= M) return;
    const int c    = lane;
    const bool act = (c < NCLASS);
    const int beg = rowptr[d];
    const int end = rowptr[d + 1];

    float acc = 0.f;
    for (int base = beg; base < end; base += 64) {
        int myе_dummy = 0; (void)myе_dummy;
        int mye = base + lane;
        int sj  = (mye < end) ? colidx[mye] : 0;
        float nsj = (mye < end) ? nrm[sj] : 0.f;
        int cnt = end - base; if (cnt > 64) cnt = 64;
        for (int j = 0; j < cnt; ++j) {
            int   s  = __shfl(sj, j);
            float ns = __shfl(nsj, j);
            if (act) acc += h[(size_t)s * NCLASS + c] * ns;
        }
    }
    float r = acc * nrm[d];
    float p = act ? r * svec[c] : 0.f;
    #pragma unroll
    for (int off = 32; off; off >>= 1) p += __shfl_xor(p, off);
    float S = 1.f / (1.f + __expf(-p));
    if (act) {
        hnext[(size_t)d * NCLASS + c] = r;
        out[(size_t)d * NCLASS + c]  += S * r;
    }
}

// ---------------------------------------------------------------------------
extern "C" void kernel_launch(void* const* d_in, const int* in_sizes, int n_in,
                              void* d_out, int out_size, void* d_ws, size_t ws_size,
                              hipStream_t stream) {
    const float* feats = (const float*)d_in[0];
    const float* W1    = (const float*)d_in[1];
    const float* b1    = (const float*)d_in[2];
    const float* W2    = (const float*)d_in[3];
    const float* b2    = (const float*)d_in[4];
    const float* svec  = (const float*)d_in[5];
    const int*   src   = (const int*)d_in[6];
    const int*   dst   = (const int*)d_in[7];
    float* out = (float*)d_out;

    const int M = in_sizes[0] / INDIM;    // 100000
    const int E = in_sizes[6];            // 1600000

    // workspace carve-up
    char* p = (char*)d_ws;
    size_t off = 0;
    float* hid   = (float*)(p + off); off += roundup256((size_t)M * HID * 4);
    float* hA    = (float*)(p + off); off += roundup256((size_t)M * NCLASS * 4);
    float* hB    = (float*)(p + off); off += roundup256((size_t)M * NCLASS * 4);
    int*   degi  = (int*)  (p + off); off += roundup256((size_t)M * 4);
    float* nrm   = (float*)(p + off); off += roundup256((size_t)M * 4);
    int*   rowptr= (int*)  (p + off); off += roundup256((size_t)(M + 1) * 4);
    int*   fillc = (int*)  (p + off); off += roundup256((size_t)M * 4);
    int*   colidx= (int*)  (p + off); off += roundup256((size_t)E * 4);
    (void)ws_size;

    // --- graph/degree prep ---
    dagnn_zero2<<<(M + 255) / 256, 256, 0, stream>>>(degi, fillc, M);
    dagnn_deg<<<(E + 255) / 256, 256, 0, stream>>>(dst, degi, E);
    dagnn_norm<<<(M + 255) / 256, 256, 0, stream>>>(degi, nrm, M);
    dagnn_scan<<<1, 1024, 0, stream>>>(degi, rowptr, M);
    dagnn_fill<<<(E + 255) / 256, 256, 0, stream>>>(src, dst, rowptr, fillc, colidx, E);

    // --- MLP ---
    dim3 g1((M + BM - 1) / BM, HID / BN);
    dagnn_gemm1<<<g1, 256, 0, stream>>>(feats, W1, b1, hid, M);
    dagnn_mlp2<<<(M + 63) / 64, 256, 0, stream>>>(hid, W2, b2, svec, hA, out, M);

    // --- K propagation hops with online output accumulation ---
    float* hin = hA;
    float* hout = hB;
    for (int k = 0; k < KHOPS; ++k) {
        dagnn_prop<<<(M + 3) / 4, 256, 0, stream>>>(hin, nrm, rowptr, colidx,
                                                    svec, hout, out, M);
        float* t = hin; hin = hout; hout = t;
    }
}

// Round 2
// 1621.047 us; speedup vs baseline: 1.7020x; 1.7020x over previous
//
#include <hip/hip_runtime.h>
#include <hip/hip_bf16.h>
#include <math.h>

// Problem dims (DAGNN_14594298872388)
#define NN     100000   // nodes
#define INDIM  500
#define HID    256
#define NCLASS 50
#define KHOPS  10
#define KPAD   512      // INDIM padded to multiple of 32 for MFMA

static inline size_t roundup256(size_t x) { return (x + 255) & ~(size_t)255; }

typedef __attribute__((ext_vector_type(8))) short bf16x8;   // 8 bf16 = 4 VGPRs
typedef __attribute__((ext_vector_type(4))) float f32x4;    // MFMA acc
typedef __attribute__((ext_vector_type(4))) short short4v;

__device__ inline short f2bf(float f) {      // fp32 -> bf16, round-nearest-even
    union { float f; unsigned u; } v; v.f = f;
    unsigned r = v.u + 0x7FFFu + ((v.u >> 16) & 1u);
    return (short)(r >> 16);
}

// ---------------------------------------------------------------------------
// prep: zero counters, degree, norm, scan, CSR fill
// ---------------------------------------------------------------------------
__global__ void dagnn_zero2(int* __restrict__ a, int* __restrict__ b, int n) {
    int i = blockIdx.x * blockDim.x + threadIdx.x;
    if (i < n) { a[i] = 0; b[i] = 0; }
}

__global__ void dagnn_deg(const int* __restrict__ dst, int* __restrict__ degi, int E) {
    int e = blockIdx.x * blockDim.x + threadIdx.x;
    if (e < E) atomicAdd(&degi[dst[e]], 1);
}

__global__ void dagnn_norm(const int* __restrict__ degi, float* __restrict__ nrm, int n) {
    int i = blockIdx.x * blockDim.x + threadIdx.x;
    if (i < n) nrm[i] = rsqrtf((float)degi[i]);   // deg >= 1 (self loop)
}

__global__ void dagnn_scan(const int* __restrict__ degi, int* __restrict__ rowptr, int n) {
    __shared__ int wsum[16];
    __shared__ int carry_s;
    const int tid  = threadIdx.x;        // 1024
    const int lane = tid & 63;
    const int wid  = tid >> 6;
    if (tid == 0) carry_s = 0;
    __syncthreads();
    for (int base = 0; base < n; base += 4096) {
        int i0 = base + tid * 4;
        int v0 = (i0 + 0 < n) ? degi[i0 + 0] : 0;
        int v1 = (i0 + 1 < n) ? degi[i0 + 1] : 0;
        int v2 = (i0 + 2 < n) ? degi[i0 + 2] : 0;
        int v3 = (i0 + 3 < n) ? degi[i0 + 3] : 0;
        int tsum = v0 + v1 + v2 + v3;
        int x = tsum;
        #pragma unroll
        for (int off = 1; off < 64; off <<= 1) {
            int t = __shfl_up(x, off);
            if (lane >= off) x += t;
        }
        if (lane == 63) wsum[wid] = x;
        __syncthreads();
        if (tid == 0) {
            int run = carry_s;
            #pragma unroll
            for (int w = 0; w < 16; ++w) { int t = wsum[w]; wsum[w] = run; run += t; }
            carry_s = run;
        }
        __syncthreads();
        int texcl = wsum[wid] + (x - tsum);
        if (i0 + 0 < n) rowptr[i0 + 0] = texcl;
        if (i0 + 1 < n) rowptr[i0 + 1] = texcl + v0;
        if (i0 + 2 < n) rowptr[i0 + 2] = texcl + v0 + v1;
        if (i0 + 3 < n) rowptr[i0 + 3] = texcl + v0 + v1 + v2;
        __syncthreads();
    }
    if (tid == 0) rowptr[n] = carry_s;
}

__global__ void dagnn_fill(const int* __restrict__ src, const int* __restrict__ dst,
                           const int* __restrict__ rowptr, int* __restrict__ fillc,
                           int* __restrict__ colidx, int E) {
    int e = blockIdx.x * blockDim.x + threadIdx.x;
    if (e >= E) return;
    int d = dst[e];
    int pos = rowptr[d] + atomicAdd(&fillc[d], 1);
    colidx[pos] = src[e];
}

// ---------------------------------------------------------------------------
// W1 [500][256] fp32 -> W1t [256][512] bf16 (transposed, zero-padded K)
// ---------------------------------------------------------------------------
__global__ void dagnn_w1t(const float* __restrict__ W1, short* __restrict__ W1t) {
    int idx = blockIdx.x * 256 + threadIdx.x;   // 256*512 = 131072
    if (idx >= HID * KPAD) return;
    int n = idx >> 9;         // 0..255
    int k = idx & (KPAD - 1); // 0..511
    float v = (k < INDIM) ? W1[(size_t)k * HID + n] : 0.f;
    W1t[idx] = f2bf(v);
}

// ---------------------------------------------------------------------------
// GEMM1 (MFMA bf16): hid = relu(feats @ W1 + b1)
// block = 512 threads (8 waves); tile 128(M) x 256(N); BK=32; K=512 (padded)
// wave w: m_half = w&1 -> 64 rows, n_q = w>>1 -> 64 cols; 4x4 of 16x16x32 MFMAs
// A converted fp32->bf16 during staging.
// ---------------------------------------------------------------------------
#define G1_STRIDE 40   // LDS row stride in bf16 units (80 B = 16B-aligned, 2-way bank alias = free)
__global__ __launch_bounds__(512) void dagnn_gemm1_mfma(
        const float* __restrict__ A, const short* __restrict__ Bt,
        const float* __restrict__ bias, float* __restrict__ C, int M) {
    __shared__ __align__(16) short As[128 * G1_STRIDE];  // 10 KB
    __shared__ __align__(16) short Bs[256 * G1_STRIDE];  // 20 KB

    const int tid  = threadIdx.x;
    const int lane = tid & 63;
    const int wid  = tid >> 6;              // 0..7
    const int l16  = lane & 15;
    const int quad = lane >> 4;             // 0..3
    const int m_off = (wid & 1) * 64;
    const int n_off = (wid >> 1) * 64;
    const int row0  = blockIdx.x * 128;

    f32x4 acc[4][4] = {};

    for (int ks = 0; ks < KPAD / 32; ++ks) {
        const int k0 = ks * 32;
        // ---- stage A: 128 rows x 32 k (fp32 -> bf16) ----
        #pragma unroll
        for (int it = 0; it < 2; ++it) {
            int slot = tid + it * 512;      // 0..1023
            int m   = slot >> 3;            // 0..127
            int seg = slot & 7;             // 4 floats each
            int gm  = row0 + m;
            int gk  = k0 + seg * 4;
            float v0 = 0.f, v1 = 0.f, v2 = 0.f, v3 = 0.f;
            if (gm < M) {
                const float* ap = A + (size_t)gm * INDIM + gk;
                if (gk + 3 < INDIM) {       // vectorizable fast path
                    float4 f = *(const float4*)ap;
                    v0 = f.x; v1 = f.y; v2 = f.z; v3 = f.w;
                } else {
                    if (gk + 0 < INDIM) v0 = ap[0];
                    if (gk + 1 < INDIM) v1 = ap[1];
                    if (gk + 2 < INDIM) v2 = ap[2];
                    if (gk + 3 < INDIM) v3 = ap[3];
                }
            }
            short4v sv; sv.x = f2bf(v0); sv.y = f2bf(v1); sv.z = f2bf(v2); sv.w = f2bf(v3);
            *(short4v*)&As[m * G1_STRIDE + seg * 4] = sv;
        }
        // ---- stage B: 256 n-rows x 32 k (already bf16, transposed) ----
        #pragma unroll
        for (int it = 0; it < 2; ++it) {
            int slot = tid + it * 512;      // 0..1023
            int n   = slot >> 2;            // 0..255
            int seg = slot & 3;             // 8 bf16 each
            bf16x8 b = *(const bf16x8*)(Bt + (size_t)n * KPAD + k0 + seg * 8);
            *(bf16x8*)&Bs[n * G1_STRIDE + seg * 8] = b;
        }
        __syncthreads();

        bf16x8 af[4], bf[4];
        #pragma unroll
        for (int mt = 0; mt < 4; ++mt)
            af[mt] = *(const bf16x8*)&As[(m_off + mt * 16 + l16) * G1_STRIDE + quad * 8];
        #pragma unroll
        for (int nt = 0; nt < 4; ++nt)
            bf[nt] = *(const bf16x8*)&Bs[(n_off + nt * 16 + l16) * G1_STRIDE + quad * 8];
        #pragma unroll
        for (int mt = 0; mt < 4; ++mt)
            #pragma unroll
            for (int nt = 0; nt < 4; ++nt)
                acc[mt][nt] = __builtin_amdgcn_mfma_f32_16x16x32_bf16(
                                  af[mt], bf[nt], acc[mt][nt], 0, 0, 0);
        __syncthreads();
    }

    // epilogue: bias + relu; C/D layout col=lane&15, row=quad*4+reg
    #pragma unroll
    for (int nt = 0; nt < 4; ++nt) {
        int gc = n_off + nt * 16 + l16;
        float bb = bias[gc];
        #pragma unroll
        for (int mt = 0; mt < 4; ++mt) {
            #pragma unroll
            for (int r = 0; r < 4; ++r) {
                int gm = row0 + m_off + mt * 16 + quad * 4 + r;
                if (gm < M) {
                    float v = acc[mt][nt][r] + bb;
                    C[(size_t)gm * HID + gc] = v > 0.f ? v : 0.f;
                }
            }
        }
    }
}

// ---------------------------------------------------------------------------
// GEMM2 + epilogue: x = hid @ W2 + b2 ; hs0 = x*nrm ; out = sigmoid(x.s)*x
// ---------------------------------------------------------------------------
__global__ __launch_bounds__(256) void dagnn_mlp2(
        const float* __restrict__ hid, const float* __restrict__ W2,
        const float* __restrict__ b2, const float* __restrict__ svec,
        const float* __restrict__ nrm,
        float* __restrict__ hs0, float* __restrict__ out, int M) {
    __shared__ float sw2[HID * NCLASS];   // 51.2 KB
    __shared__ float sb2[64];
    __shared__ float ss[64];
    const int tid = threadIdx.x;
    for (int i = tid; i < HID * NCLASS; i += 256) sw2[i] = W2[i];
    if (tid < 64) {
        sb2[tid] = (tid < NCLASS) ? b2[tid] : 0.f;
        ss[tid]  = (tid < NCLASS) ? svec[tid] : 0.f;
    }
    __syncthreads();

    const int c    = tid & 63;
    const int rg   = tid >> 6;                 // wave id 0..3
    const int row0 = blockIdx.x * 64 + rg * 16;
    const bool act = (c < NCLASS);

    int roff[16];
    #pragma unroll
    for (int r = 0; r < 16; ++r) {
        int row = row0 + r;
        if (row >= M) row = M - 1;             // clamp (stores guarded)
        roff[r] = row * HID;
    }

    float acc[16];
    #pragma unroll
    for (int r = 0; r < 16; ++r) acc[r] = 0.f;

    for (int k = 0; k < HID; ++k) {
        float w = act ? sw2[k * NCLASS + c] : 0.f;
        #pragma unroll
        for (int r = 0; r < 16; ++r)
            acc[r] += hid[(size_t)roff[r] + k] * w;   // wave-uniform broadcast load
    }

    #pragma unroll
    for (int r = 0; r < 16; ++r) {
        int row = row0 + r;
        float v = acc[r] + sb2[c];
        float p = act ? v * ss[c] : 0.f;
        #pragma unroll
        for (int off = 32; off; off >>= 1) p += __shfl_xor(p, off);
        float S = 1.f / (1.f + __expf(-p));
        if (act && row < M) {
            float nd = nrm[row];
            hs0[(size_t)row * NCLASS + c] = v * nd;   // pre-scaled gather source
            out[(size_t)row * NCLASS + c] = S * v;
        }
    }
}

// ---------------------------------------------------------------------------
// propagation hop, v2: gather from pre-scaled hs (= h * nrm)
//   r[d]       = nrm[d] * sum_{s in N(d)} hs[s]
//   hs_next[d] = r * nrm[d]        (pre-scale for next hop)
//   out[d]    += sigmoid(r . s) * r
// one wave per dst row; lanes = channels; neighbor loop unrolled x4 for MLP
// ---------------------------------------------------------------------------
__global__ __launch_bounds__(256) void dagnn_prop2(
        const float* __restrict__ hs, const float* __restrict__ nrm,
        const int* __restrict__ rowptr, const int* __restrict__ colidx,
        const float* __restrict__ svec, float* __restrict__ hs_next,
        float* __restrict__ out, int M) {
    const int lane = threadIdx.x & 63;
    const int wid  = threadIdx.x >> 6;
    const int d    = blockIdx.x * 4 + wid;
    if (d >= M) return;
    const int c    = lane;
    const bool act = (c < NCLASS);
    const int beg = rowptr[d];
    const int end = rowptr[d + 1];

    float acc = 0.f;
    int e = beg;
    for (; e + 4 <= end; e += 4) {
        int s0 = colidx[e + 0];       // wave-uniform -> scalar loads
        int s1 = colidx[e + 1];
        int s2 = colidx[e + 2];
        int s3 = colidx[e + 3];
        if (act) {
            float v0 = hs[(size_t)s0 * NCLASS + c];
            float v1 = hs[(size_t)s1 * NCLASS + c];
            float v2 = hs[(size_t)s2 * NCLASS + c];
            float v3 = hs[(size_t)s3 * NCLASS + c];
            acc += v0; acc += v1; acc += v2; acc += v3;
        }
    }
    for (; e < end; ++e) {
        int s = colidx[e];
        if (act) acc += hs[(size_t)s * NCLASS + c];
    }

    float nd = nrm[d];
    float r = acc * nd;
    float p = act ? r * svec[c] : 0.f;
    #pragma unroll
    for (int off = 32; off; off >>= 1) p += __shfl_xor(p, off);
    float S = 1.f / (1.f + __expf(-p));
    if (act) {
        hs_next[(size_t)d * NCLASS + c] = r * nd;
        out[(size_t)d * NCLASS + c]    += S * r;
    }
}

// ---------------------------------------------------------------------------
extern "C" void kernel_launch(void* const* d_in, const int* in_sizes, int n_in,
                              void* d_out, int out_size, void* d_ws, size_t ws_size,
                              hipStream_t stream) {
    const float* feats = (const float*)d_in[0];
    const float* W1    = (const float*)d_in[1];
    const float* b1    = (const float*)d_in[2];
    const float* W2    = (const float*)d_in[3];
    const float* b2    = (const float*)d_in[4];
    const float* svec  = (const float*)d_in[5];
    const int*   src   = (const int*)d_in[6];
    const int*   dst   = (const int*)d_in[7];
    float* out = (float*)d_out;

    const int M = in_sizes[0] / INDIM;    // 100000
    const int E = in_sizes[6];            // 1600000

    // workspace carve-up
    char* p = (char*)d_ws;
    size_t off = 0;
    float* hid   = (float*)(p + off); off += roundup256((size_t)M * HID * 4);
    float* hsA   = (float*)(p + off); off += roundup256((size_t)M * NCLASS * 4);
    float* hsB   = (float*)(p + off); off += roundup256((size_t)M * NCLASS * 4);
    short* W1t   = (short*)(p + off); off += roundup256((size_t)HID * KPAD * 2);
    int*   degi  = (int*)  (p + off); off += roundup256((size_t)M * 4);
    float* nrm   = (float*)(p + off); off += roundup256((size_t)M * 4);
    int*   rowptr= (int*)  (p + off); off += roundup256((size_t)(M + 1) * 4);
    int*   fillc = (int*)  (p + off); off += roundup256((size_t)M * 4);
    int*   colidx= (int*)  (p + off); off += roundup256((size_t)E * 4);
    (void)ws_size;

    // --- graph/degree prep ---
    dagnn_zero2<<<(M + 255) / 256, 256, 0, stream>>>(degi, fillc, M);
    dagnn_deg<<<(E + 255) / 256, 256, 0, stream>>>(dst, degi, E);
    dagnn_norm<<<(M + 255) / 256, 256, 0, stream>>>(degi, nrm, M);
    dagnn_scan<<<1, 1024, 0, stream>>>(degi, rowptr, M);
    dagnn_fill<<<(E + 255) / 256, 256, 0, stream>>>(src, dst, rowptr, fillc, colidx, E);

    // --- W1 transpose+convert, then MFMA GEMM1 ---
    dagnn_w1t<<<(HID * KPAD + 255) / 256, 256, 0, stream>>>(W1, W1t);
    dagnn_gemm1_mfma<<<(M + 127) / 128, 512, 0, stream>>>(feats, W1t, b1, hid, M);

    // --- GEMM2 + gate epilogue (writes pre-scaled hs0) ---
    dagnn_mlp2<<<(M + 63) / 64, 256, 0, stream>>>(hid, W2, b2, svec, nrm, hsA, out, M);

    // --- K propagation hops with online output accumulation ---
    float* hin = hsA;
    float* hout = hsB;
    for (int k = 0; k < KHOPS; ++k) {
        dagnn_prop2<<<(M + 3) / 4, 256, 0, stream>>>(hin, nrm, rowptr, colidx,
                                                     svec, hout, out, M);
        float* t = hin; hin = hout; hout = t;
    }
}

// Round 3
// 1379.525 us; speedup vs baseline: 2.0000x; 1.1751x over previous
//
#include <hip/hip_runtime.h>
#include <hip/hip_bf16.h>
#include <math.h>

// Problem dims (DAGNN_14594298872388)
#define NN     100000   // nodes
#define INDIM  500
#define HID    256
#define NCLASS 50
#define KHOPS  10
#define KPAD   512      // INDIM padded to multiple of 32 for MFMA
#define CPAD   64       // NCLASS padded for prop gather + mlp2 MFMA N

static inline size_t roundup256(size_t x) { return (x + 255) & ~(size_t)255; }

typedef __attribute__((ext_vector_type(8))) short bf16x8;   // 8 bf16 = 4 VGPRs
typedef __attribute__((ext_vector_type(4))) float f32x4;    // MFMA acc
typedef __attribute__((ext_vector_type(4))) short short4v;

__device__ inline short f2bf(float f) {      // fp32 -> bf16, round-nearest-even
    union { float f; unsigned u; } v; v.f = f;
    unsigned r = v.u + 0x7FFFu + ((v.u >> 16) & 1u);
    return (short)(r >> 16);
}

// ---------------------------------------------------------------------------
// prep: zero counters, degree, norm, scan, CSR fill
// ---------------------------------------------------------------------------
__global__ void dagnn_zero2(int* __restrict__ a, int* __restrict__ b, int n) {
    int i = blockIdx.x * blockDim.x + threadIdx.x;
    if (i < n) { a[i] = 0; b[i] = 0; }
}

__global__ void dagnn_deg(const int* __restrict__ dst, int* __restrict__ degi, int E) {
    int e = blockIdx.x * blockDim.x + threadIdx.x;
    if (e < E) atomicAdd(&degi[dst[e]], 1);
}

__global__ void dagnn_norm(const int* __restrict__ degi, float* __restrict__ nrm, int n) {
    int i = blockIdx.x * blockDim.x + threadIdx.x;
    if (i < n) nrm[i] = rsqrtf((float)degi[i]);   // deg >= 1 (self loop)
}

__global__ void dagnn_scan(const int* __restrict__ degi, int* __restrict__ rowptr, int n) {
    __shared__ int wsum[16];
    __shared__ int carry_s;
    const int tid  = threadIdx.x;        // 1024
    const int lane = tid & 63;
    const int wid  = tid >> 6;
    if (tid == 0) carry_s = 0;
    __syncthreads();
    for (int base = 0; base < n; base += 4096) {
        int i0 = base + tid * 4;
        int v0 = (i0 + 0 < n) ? degi[i0 + 0] : 0;
        int v1 = (i0 + 1 < n) ? degi[i0 + 1] : 0;
        int v2 = (i0 + 2 < n) ? degi[i0 + 2] : 0;
        int v3 = (i0 + 3 < n) ? degi[i0 + 3] : 0;
        int tsum = v0 + v1 + v2 + v3;
        int x = tsum;
        #pragma unroll
        for (int off = 1; off < 64; off <<= 1) {
            int t = __shfl_up(x, off);
            if (lane >= off) x += t;
        }
        if (lane == 63) wsum[wid] = x;
        __syncthreads();
        if (tid == 0) {
            int run = carry_s;
            #pragma unroll
            for (int w = 0; w < 16; ++w) { int t = wsum[w]; wsum[w] = run; run += t; }
            carry_s = run;
        }
        __syncthreads();
        int texcl = wsum[wid] + (x - tsum);
        if (i0 + 0 < n) rowptr[i0 + 0] = texcl;
        if (i0 + 1 < n) rowptr[i0 + 1] = texcl + v0;
        if (i0 + 2 < n) rowptr[i0 + 2] = texcl + v0 + v1;
        if (i0 + 3 < n) rowptr[i0 + 3] = texcl + v0 + v1 + v2;
        __syncthreads();
    }
    if (tid == 0) rowptr[n] = carry_s;
}

__global__ void dagnn_fill(const int* __restrict__ src, const int* __restrict__ dst,
                           const int* __restrict__ rowptr, int* __restrict__ fillc,
                           int* __restrict__ colidx, int E) {
    int e = blockIdx.x * blockDim.x + threadIdx.x;
    if (e >= E) return;
    int d = dst[e];
    int pos = rowptr[d] + atomicAdd(&fillc[d], 1);
    colidx[pos] = src[e];
}

// ---------------------------------------------------------------------------
// W1 [500][256] fp32 -> W1t [256][512] bf16 (transposed, zero-padded K)
// ---------------------------------------------------------------------------
__global__ void dagnn_w1t(const float* __restrict__ W1, short* __restrict__ W1t) {
    int idx = blockIdx.x * 256 + threadIdx.x;   // 256*512 = 131072
    if (idx >= HID * KPAD) return;
    int n = idx >> 9;         // 0..255
    int k = idx & (KPAD - 1); // 0..511
    float v = (k < INDIM) ? W1[(size_t)k * HID + n] : 0.f;
    W1t[idx] = f2bf(v);
}

// ---------------------------------------------------------------------------
// W2 [256][50] fp32 -> W2t [64][256] bf16 (transposed, zero-padded N)
// ---------------------------------------------------------------------------
__global__ void dagnn_w2t(const float* __restrict__ W2, short* __restrict__ W2t) {
    int idx = blockIdx.x * 256 + threadIdx.x;   // 64*256 = 16384
    if (idx >= CPAD * HID) return;
    int n = idx >> 8;         // 0..63
    int k = idx & 255;        // 0..255
    float v = (n < NCLASS) ? W2[(size_t)k * NCLASS + n] : 0.f;
    W2t[idx] = f2bf(v);
}

// ---------------------------------------------------------------------------
// GEMM1 (MFMA bf16): hid = relu(feats @ W1 + b1), output bf16
// block = 512 threads (8 waves); tile 128(M) x 256(N); BK=32; K=512 (padded)
// ---------------------------------------------------------------------------
#define G1_STRIDE 40   // LDS row stride in bf16 units (80 B; 2-way bank alias = free)
__global__ __launch_bounds__(512) void dagnn_gemm1_mfma(
        const float* __restrict__ A, const short* __restrict__ Bt,
        const float* __restrict__ bias, short* __restrict__ C, int M) {
    __shared__ __align__(16) short As[128 * G1_STRIDE];  // 10 KB
    __shared__ __align__(16) short Bs[256 * G1_STRIDE];  // 20 KB

    const int tid  = threadIdx.x;
    const int lane = tid & 63;
    const int wid  = tid >> 6;              // 0..7
    const int l16  = lane & 15;
    const int quad = lane >> 4;             // 0..3
    const int m_off = (wid & 1) * 64;
    const int n_off = (wid >> 1) * 64;
    const int row0  = blockIdx.x * 128;

    f32x4 acc[4][4] = {};

    for (int ks = 0; ks < KPAD / 32; ++ks) {
        const int k0 = ks * 32;
        // ---- stage A: 128 rows x 32 k (fp32 -> bf16) ----
        #pragma unroll
        for (int it = 0; it < 2; ++it) {
            int slot = tid + it * 512;      // 0..1023
            int m   = slot >> 3;            // 0..127
            int seg = slot & 7;             // 4 floats each
            int gm  = row0 + m;
            int gk  = k0 + seg * 4;
            float v0 = 0.f, v1 = 0.f, v2 = 0.f, v3 = 0.f;
            if (gm < M) {
                const float* ap = A + (size_t)gm * INDIM + gk;
                if (gk + 3 < INDIM) {
                    float4 f = *(const float4*)ap;
                    v0 = f.x; v1 = f.y; v2 = f.z; v3 = f.w;
                } else {
                    if (gk + 0 < INDIM) v0 = ap[0];
                    if (gk + 1 < INDIM) v1 = ap[1];
                    if (gk + 2 < INDIM) v2 = ap[2];
                    if (gk + 3 < INDIM) v3 = ap[3];
                }
            }
            short4v sv; sv.x = f2bf(v0); sv.y = f2bf(v1); sv.z = f2bf(v2); sv.w = f2bf(v3);
            *(short4v*)&As[m * G1_STRIDE + seg * 4] = sv;
        }
        // ---- stage B: 256 n-rows x 32 k (already bf16, transposed) ----
        #pragma unroll
        for (int it = 0; it < 2; ++it) {
            int slot = tid + it * 512;      // 0..1023
            int n   = slot >> 2;            // 0..255
            int seg = slot & 3;             // 8 bf16 each
            bf16x8 b = *(const bf16x8*)(Bt + (size_t)n * KPAD + k0 + seg * 8);
            *(bf16x8*)&Bs[n * G1_STRIDE + seg * 8] = b;
        }
        __syncthreads();

        bf16x8 af[4], bf[4];
        #pragma unroll
        for (int mt = 0; mt < 4; ++mt)
            af[mt] = *(const bf16x8*)&As[(m_off + mt * 16 + l16) * G1_STRIDE + quad * 8];
        #pragma unroll
        for (int nt = 0; nt < 4; ++nt)
            bf[nt] = *(const bf16x8*)&Bs[(n_off + nt * 16 + l16) * G1_STRIDE + quad * 8];
        #pragma unroll
        for (int mt = 0; mt < 4; ++mt)
            #pragma unroll
            for (int nt = 0; nt < 4; ++nt)
                acc[mt][nt] = __builtin_amdgcn_mfma_f32_16x16x32_bf16(
                                  af[mt], bf[nt], acc[mt][nt], 0, 0, 0);
        __syncthreads();
    }

    // epilogue: bias + relu -> bf16; C/D layout col=lane&15, row=quad*4+reg
    #pragma unroll
    for (int nt = 0; nt < 4; ++nt) {
        int gc = n_off + nt * 16 + l16;
        float bb = bias[gc];
        #pragma unroll
        for (int mt = 0; mt < 4; ++mt) {
            #pragma unroll
            for (int r = 0; r < 4; ++r) {
                int gm = row0 + m_off + mt * 16 + quad * 4 + r;
                if (gm < M) {
                    float v = acc[mt][nt][r] + bb;
                    C[(size_t)gm * HID + gc] = f2bf(v > 0.f ? v : 0.f);
                }
            }
        }
    }
}

// ---------------------------------------------------------------------------
// GEMM2 (MFMA) + gate epilogue:
//   x = hid(bf16) @ W2 + b2 ; hs0 = x*nrm (padded 64) ; out = sigmoid(x.s)*x
// block = 256 threads (4 waves); tile 128(M) x 64(N); K=256, BK=64
// wave w owns rows w*32..w*32+31 (2 m-tiles) x all 64 cols (4 n-tiles)
// ---------------------------------------------------------------------------
#define A2_STRIDE 72    // 128 rows x (64+8) shorts = 18432 B
#define B2_STRIDE 264   // 64 rows x (256+8) shorts = 33792 B
__global__ __launch_bounds__(256) void dagnn_mlp2_mfma(
        const short* __restrict__ hid, const short* __restrict__ W2t,
        const float* __restrict__ b2, const float* __restrict__ svec,
        const float* __restrict__ nrm,
        float* __restrict__ hs0, float* __restrict__ out, int M) {
    __shared__ __align__(16) short As[128 * A2_STRIDE];
    __shared__ __align__(16) short Bs[CPAD * B2_STRIDE];

    const int tid  = threadIdx.x;
    const int lane = tid & 63;
    const int wid  = tid >> 6;              // 0..3
    const int l16  = lane & 15;
    const int quad = lane >> 4;
    const int m_off = wid * 32;
    const int row0  = blockIdx.x * 128;

    // stage all of W2t (64 x 256) into LDS once
    #pragma unroll
    for (int it = 0; it < 8; ++it) {
        int slot = tid + it * 256;          // 0..2047
        int n   = slot >> 5;                // 0..63
        int seg = slot & 31;                // 8 bf16 each
        bf16x8 b = *(const bf16x8*)(W2t + (size_t)n * HID + seg * 8);
        *(bf16x8*)&Bs[n * B2_STRIDE + seg * 8] = b;
    }

    f32x4 acc[2][4] = {};

    for (int ks = 0; ks < HID / 64; ++ks) {     // 4 iterations, BK=64
        const int k0 = ks * 64;
        // stage A: 128 rows x 64 k (bf16 copy)
        #pragma unroll
        for (int it = 0; it < 4; ++it) {
            int slot = tid + it * 256;      // 0..1023
            int m   = slot >> 3;            // 0..127
            int seg = slot & 7;             // 8 bf16 each
            int gm  = row0 + m;
            bf16x8 v = {};
            if (gm < M) v = *(const bf16x8*)(hid + (size_t)gm * HID + k0 + seg * 8);
            *(bf16x8*)&As[m * A2_STRIDE + seg * 8] = v;
        }
        __syncthreads();

        #pragma unroll
        for (int ksub = 0; ksub < 2; ++ksub) {
            bf16x8 af[2], bf[4];
            #pragma unroll
            for (int mt = 0; mt < 2; ++mt)
                af[mt] = *(const bf16x8*)&As[(m_off + mt * 16 + l16) * A2_STRIDE
                                             + ksub * 32 + quad * 8];
            #pragma unroll
            for (int nt = 0; nt < 4; ++nt)
                bf[nt] = *(const bf16x8*)&Bs[(nt * 16 + l16) * B2_STRIDE
                                             + k0 + ksub * 32 + quad * 8];
            #pragma unroll
            for (int mt = 0; mt < 2; ++mt)
                #pragma unroll
                for (int nt = 0; nt < 4; ++nt)
                    acc[mt][nt] = __builtin_amdgcn_mfma_f32_16x16x32_bf16(
                                      af[mt], bf[nt], acc[mt][nt], 0, 0, 0);
        }
        __syncthreads();
    }

    // epilogue: per lane, cols gc = nt*16+l16; rows quad*4+r per m-tile
    float b2v[4], ssv[4];
    #pragma unroll
    for (int nt = 0; nt < 4; ++nt) {
        int gc = nt * 16 + l16;
        b2v[nt] = (gc < NCLASS) ? b2[gc]   : 0.f;
        ssv[nt] = (gc < NCLASS) ? svec[gc] : 0.f;
    }
    #pragma unroll
    for (int mt = 0; mt < 2; ++mt) {
        #pragma unroll
        for (int r = 0; r < 4; ++r) {
            int gm = row0 + m_off + mt * 16 + quad * 4 + r;
            float xv[4], q = 0.f;
            #pragma unroll
            for (int nt = 0; nt < 4; ++nt) {
                xv[nt] = acc[mt][nt][r] + b2v[nt];
                q += xv[nt] * ssv[nt];
            }
            #pragma unroll
            for (int off = 1; off < 16; off <<= 1) q += __shfl_xor(q, off);
            float S = 1.f / (1.f + __expf(-q));
            if (gm < M) {
                float nd = nrm[gm];
                #pragma unroll
                for (int nt = 0; nt < 4; ++nt) {
                    int gc = nt * 16 + l16;
                    hs0[(size_t)gm * CPAD + gc] = xv[nt] * nd;   // pad cols = 0
                    if (gc < NCLASS) out[(size_t)gm * NCLASS + gc] = S * xv[nt];
                }
            }
        }
    }
}

// ---------------------------------------------------------------------------
// propagation hop: gather from pre-scaled padded hs (= h * nrm, [M][64])
//   r[d]       = nrm[d] * sum_{s in N(d)} hs[s]
//   hs_next[d] = r * nrm[d]
//   out[d]    += sigmoid(r . s) * r
// one wave per dst row; all 64 lanes active (pad lanes carry zeros)
// ---------------------------------------------------------------------------
__global__ __launch_bounds__(256) void dagnn_prop3(
        const float* __restrict__ hs, const float* __restrict__ nrm,
        const int* __restrict__ rowptr, const int* __restrict__ colidx,
        const float* __restrict__ svec, float* __restrict__ hs_next,
        float* __restrict__ out, int M) {
    const int lane = threadIdx.x & 63;
    const int wid  = threadIdx.x >> 6;
    const int d    = blockIdx.x * 4 + wid;
    if (d >= M) return;
    const int c   = lane;
    const int beg = rowptr[d];
    const int end = rowptr[d + 1];

    float acc = 0.f;
    int e = beg;
    for (; e + 8 <= end; e += 8) {
        int s0 = colidx[e + 0];       // wave-uniform -> scalar loads
        int s1 = colidx[e + 1];
        int s2 = colidx[e + 2];
        int s3 = colidx[e + 3];
        int s4 = colidx[e + 4];
        int s5 = colidx[e + 5];
        int s6 = colidx[e + 6];
        int s7 = colidx[e + 7];
        float v0 = hs[(size_t)s0 * CPAD + c];
        float v1 = hs[(size_t)s1 * CPAD + c];
        float v2 = hs[(size_t)s2 * CPAD + c];
        float v3 = hs[(size_t)s3 * CPAD + c];
        float v4 = hs[(size_t)s4 * CPAD + c];
        float v5 = hs[(size_t)s5 * CPAD + c];
        float v6 = hs[(size_t)s6 * CPAD + c];
        float v7 = hs[(size_t)s7 * CPAD + c];
        acc += ((v0 + v1) + (v2 + v3)) + ((v4 + v5) + (v6 + v7));
    }
    for (; e < end; ++e) {
        int s = colidx[e];
        acc += hs[(size_t)s * CPAD + c];
    }

    float nd = nrm[d];
    float r = acc * nd;
    float ss = (c < NCLASS) ? svec[c] : 0.f;
    float p = r * ss;
    #pragma unroll
    for (int off = 32; off; off >>= 1) p += __shfl_xor(p, off);
    float S = 1.f / (1.f + __expf(-p));
    hs_next[(size_t)d * CPAD + c] = r * nd;   // pad lanes write 0
    if (c < NCLASS) out[(size_t)d * NCLASS + c] += S * r;
}

// ---------------------------------------------------------------------------
extern "C" void kernel_launch(void* const* d_in, const int* in_sizes, int n_in,
                              void* d_out, int out_size, void* d_ws, size_t ws_size,
                              hipStream_t stream) {
    const float* feats = (const float*)d_in[0];
    const float* W1    = (const float*)d_in[1];
    const float* b1    = (const float*)d_in[2];
    const float* W2    = (const float*)d_in[3];
    const float* b2    = (const float*)d_in[4];
    const float* svec  = (const float*)d_in[5];
    const int*   src   = (const int*)d_in[6];
    const int*   dst   = (const int*)d_in[7];
    float* out = (float*)d_out;

    const int M = in_sizes[0] / INDIM;    // 100000
    const int E = in_sizes[6];            // 1600000

    // workspace carve-up
    char* p = (char*)d_ws;
    size_t off = 0;
    short* hid   = (short*)(p + off); off += roundup256((size_t)M * HID * 2);
    float* hsA   = (float*)(p + off); off += roundup256((size_t)M * CPAD * 4);
    float* hsB   = (float*)(p + off); off += roundup256((size_t)M * CPAD * 4);
    short* W1t   = (short*)(p + off); off += roundup256((size_t)HID * KPAD * 2);
    short* W2t   = (short*)(p + off); off += roundup256((size_t)CPAD * HID * 2);
    int*   degi  = (int*)  (p + off); off += roundup256((size_t)M * 4);
    float* nrm   = (float*)(p + off); off += roundup256((size_t)M * 4);
    int*   rowptr= (int*)  (p + off); off += roundup256((size_t)(M + 1) * 4);
    int*   fillc = (int*)  (p + off); off += roundup256((size_t)M * 4);
    int*   colidx= (int*)  (p + off); off += roundup256((size_t)E * 4);
    (void)ws_size;

    // --- graph/degree prep ---
    dagnn_zero2<<<(M + 255) / 256, 256, 0, stream>>>(degi, fillc, M);
    dagnn_deg<<<(E + 255) / 256, 256, 0, stream>>>(dst, degi, E);
    dagnn_norm<<<(M + 255) / 256, 256, 0, stream>>>(degi, nrm, M);
    dagnn_scan<<<1, 1024, 0, stream>>>(degi, rowptr, M);
    dagnn_fill<<<(E + 255) / 256, 256, 0, stream>>>(src, dst, rowptr, fillc, colidx, E);

    // --- weight prep ---
    dagnn_w1t<<<(HID * KPAD + 255) / 256, 256, 0, stream>>>(W1, W1t);
    dagnn_w2t<<<(CPAD * HID + 255) / 256, 256, 0, stream>>>(W2, W2t);

    // --- MLP ---
    dagnn_gemm1_mfma<<<(M + 127) / 128, 512, 0, stream>>>(feats, W1t, b1, hid, M);
    dagnn_mlp2_mfma<<<(M + 127) / 128, 256, 0, stream>>>(hid, W2t, b2, svec, nrm,
                                                         hsA, out, M);

    // --- K propagation hops with online output accumulation ---
    float* hin = hsA;
    float* hout = hsB;
    for (int k = 0; k < KHOPS; ++k) {
        dagnn_prop3<<<(M + 3) / 4, 256, 0, stream>>>(hin, nrm, rowptr, colidx,
                                                     svec, hout, out, M);
        float* t = hin; hin = hout; hout = t;
    }
}

// Round 4
// 1176.103 us; speedup vs baseline: 2.3460x; 1.1730x over previous
//
#include <hip/hip_runtime.h>
#include <hip/hip_bf16.h>
#include <math.h>

// Problem dims (DAGNN_14594298872388)
#define NN     100000   // nodes
#define INDIM  500
#define HID    256
#define NCLASS 50
#define KHOPS  10
#define KPAD   512      // INDIM padded to multiple of 32 for MFMA
#define CPAD   64       // NCLASS padded (32 packed bf16 pairs per node row)

static inline size_t roundup256(size_t x) { return (x + 255) & ~(size_t)255; }

typedef __attribute__((ext_vector_type(8))) short bf16x8;   // 8 bf16 = 4 VGPRs
typedef __attribute__((ext_vector_type(4))) float f32x4;    // MFMA acc
typedef __attribute__((ext_vector_type(4))) short short4v;

__device__ inline short f2bf(float f) {      // fp32 -> bf16, round-nearest-even
    union { float f; unsigned u; } v; v.f = f;
    unsigned r = v.u + 0x7FFFu + ((v.u >> 16) & 1u);
    return (short)(r >> 16);
}
__device__ inline float bflo(unsigned u) {   // low bf16 of packed pair -> fp32
    union { unsigned u; float f; } v; v.u = u << 16; return v.f;
}
__device__ inline float bfhi(unsigned u) {   // high bf16 of packed pair -> fp32
    union { unsigned u; float f; } v; v.u = u & 0xFFFF0000u; return v.f;
}
__device__ inline unsigned packbf(float a, float b) {
    return (unsigned)(unsigned short)f2bf(a) | ((unsigned)(unsigned short)f2bf(b) << 16);
}

// ---------------------------------------------------------------------------
// prep: zero counters, degree, norm, scan, CSR fill
// ---------------------------------------------------------------------------
__global__ void dagnn_zero2(int* __restrict__ a, int* __restrict__ b, int n) {
    int i = blockIdx.x * blockDim.x + threadIdx.x;
    if (i < n) { a[i] = 0; b[i] = 0; }
}

__global__ void dagnn_deg(const int* __restrict__ dst, int* __restrict__ degi, int E) {
    int e = blockIdx.x * blockDim.x + threadIdx.x;
    if (e < E) atomicAdd(&degi[dst[e]], 1);
}

__global__ void dagnn_norm(const int* __restrict__ degi, float* __restrict__ nrm, int n) {
    int i = blockIdx.x * blockDim.x + threadIdx.x;
    if (i < n) nrm[i] = rsqrtf((float)degi[i]);   // deg >= 1 (self loop)
}

__global__ void dagnn_scan(const int* __restrict__ degi, int* __restrict__ rowptr, int n) {
    __shared__ int wsum[16];
    __shared__ int carry_s;
    const int tid  = threadIdx.x;        // 1024
    const int lane = tid & 63;
    const int wid  = tid >> 6;
    if (tid == 0) carry_s = 0;
    __syncthreads();
    for (int base = 0; base < n; base += 4096) {
        int i0 = base + tid * 4;
        int v0 = (i0 + 0 < n) ? degi[i0 + 0] : 0;
        int v1 = (i0 + 1 < n) ? degi[i0 + 1] : 0;
        int v2 = (i0 + 2 < n) ? degi[i0 + 2] : 0;
        int v3 = (i0 + 3 < n) ? degi[i0 + 3] : 0;
        int tsum = v0 + v1 + v2 + v3;
        int x = tsum;
        #pragma unroll
        for (int off = 1; off < 64; off <<= 1) {
            int t = __shfl_up(x, off);
            if (lane >= off) x += t;
        }
        if (lane == 63) wsum[wid] = x;
        __syncthreads();
        if (tid == 0) {
            int run = carry_s;
            #pragma unroll
            for (int w = 0; w < 16; ++w) { int t = wsum[w]; wsum[w] = run; run += t; }
            carry_s = run;
        }
        __syncthreads();
        int texcl = wsum[wid] + (x - tsum);
        if (i0 + 0 < n) rowptr[i0 + 0] = texcl;
        if (i0 + 1 < n) rowptr[i0 + 1] = texcl + v0;
        if (i0 + 2 < n) rowptr[i0 + 2] = texcl + v0 + v1;
        if (i0 + 3 < n) rowptr[i0 + 3] = texcl + v0 + v1 + v2;
        __syncthreads();
    }
    if (tid == 0) rowptr[n] = carry_s;
}

__global__ void dagnn_fill(const int* __restrict__ src, const int* __restrict__ dst,
                           const int* __restrict__ rowptr, int* __restrict__ fillc,
                           int* __restrict__ colidx, int E) {
    int e = blockIdx.x * blockDim.x + threadIdx.x;
    if (e >= E) return;
    int d = dst[e];
    int pos = rowptr[d] + atomicAdd(&fillc[d], 1);
    colidx[pos] = src[e];
}

// ---------------------------------------------------------------------------
// W1 [500][256] fp32 -> W1t [256][512] bf16 (transposed, zero-padded K)
// ---------------------------------------------------------------------------
__global__ void dagnn_w1t(const float* __restrict__ W1, short* __restrict__ W1t) {
    int idx = blockIdx.x * 256 + threadIdx.x;   // 256*512 = 131072
    if (idx >= HID * KPAD) return;
    int n = idx >> 9;         // 0..255
    int k = idx & (KPAD - 1); // 0..511
    float v = (k < INDIM) ? W1[(size_t)k * HID + n] : 0.f;
    W1t[idx] = f2bf(v);
}

// ---------------------------------------------------------------------------
// W2 [256][50] fp32 -> W2t [64][256] bf16 (transposed, zero-padded N)
// ---------------------------------------------------------------------------
__global__ void dagnn_w2t(const float* __restrict__ W2, short* __restrict__ W2t) {
    int idx = blockIdx.x * 256 + threadIdx.x;   // 64*256 = 16384
    if (idx >= CPAD * HID) return;
    int n = idx >> 8;         // 0..63
    int k = idx & 255;        // 0..255
    float v = (n < NCLASS) ? W2[(size_t)k * NCLASS + n] : 0.f;
    W2t[idx] = f2bf(v);
}

// sgate[c] = (s[2c], s[2c+1]) zero-padded; 32 entries
__global__ void dagnn_sgate(const float* __restrict__ svec, float2* __restrict__ sg) {
    int c = threadIdx.x;
    if (c < 32) {
        float x = (2 * c     < NCLASS) ? svec[2 * c]     : 0.f;
        float y = (2 * c + 1 < NCLASS) ? svec[2 * c + 1] : 0.f;
        sg[c] = make_float2(x, y);
    }
}

// ---------------------------------------------------------------------------
// GEMM1 (MFMA bf16, software-pipelined): hid = relu(feats @ W1 + b1), bf16 out
// block = 512 threads (8 waves); tile 128(M) x 256(N); BK=32; K=512 (padded)
// register-prefetch of tile k+1 overlaps the MFMAs + barriers of tile k
// ---------------------------------------------------------------------------
#define G1_STRIDE 40   // LDS row stride in bf16 units (80 B)
__global__ __launch_bounds__(512) void dagnn_gemm1_mfma(
        const float* __restrict__ A, const short* __restrict__ Bt,
        const float* __restrict__ bias, short* __restrict__ C, int M) {
    __shared__ __align__(16) short As[128 * G1_STRIDE];  // 10 KB
    __shared__ __align__(16) short Bs[256 * G1_STRIDE];  // 20 KB

    const int tid  = threadIdx.x;
    const int lane = tid & 63;
    const int wid  = tid >> 6;              // 0..7
    const int l16  = lane & 15;
    const int quad = lane >> 4;             // 0..3
    const int m_off = (wid & 1) * 64;
    const int n_off = (wid >> 1) * 64;
    const int row0  = blockIdx.x * 128;

    // staging slot decode (constant per thread): 2 A slots + 2 B slots
    int am[2], aseg[2], bn[2], bseg[2];
    #pragma unroll
    for (int it = 0; it < 2; ++it) {
        int slot = tid + it * 512;          // 0..1023
        am[it] = slot >> 3; aseg[it] = slot & 7;   // A: 128 rows x 8 segs(4 f32)
        bn[it] = slot >> 2; bseg[it] = slot & 3;   // B: 256 rows x 4 segs(8 bf16)
    }

    float4 ra[2]; bf16x8 rb[2];

    #define LOAD_TILE(k0)                                                     \
        _Pragma("unroll")                                                     \
        for (int it = 0; it < 2; ++it) {                                      \
            int gm = row0 + am[it];                                           \
            int gk = (k0) + aseg[it] * 4;                                     \
            float4 f = {0.f, 0.f, 0.f, 0.f};                                  \
            if (gm < M) {                                                     \
                const float* ap = A + (size_t)gm * INDIM + gk;                \
                if (gk + 3 < INDIM) f = *(const float4*)ap;                   \
                else {                                                        \
                    if (gk + 0 < INDIM) f.x = ap[0];                          \
                    if (gk + 1 < INDIM) f.y = ap[1];                          \
                    if (gk + 2 < INDIM) f.z = ap[2];                          \
                    if (gk + 3 < INDIM) f.w = ap[3];                          \
                }                                                             \
            }                                                                 \
            ra[it] = f;                                                       \
            rb[it] = *(const bf16x8*)(Bt + (size_t)bn[it] * KPAD + (k0) + bseg[it] * 8); \
        }

    #define STORE_TILE()                                                      \
        _Pragma("unroll")                                                     \
        for (int it = 0; it < 2; ++it) {                                      \
            short4v sv;                                                       \
            sv.x = f2bf(ra[it].x); sv.y = f2bf(ra[it].y);                     \
            sv.z = f2bf(ra[it].z); sv.w = f2bf(ra[it].w);                     \
            *(short4v*)&As[am[it] * G1_STRIDE + aseg[it] * 4] = sv;           \
            *(bf16x8*)&Bs[bn[it] * G1_STRIDE + bseg[it] * 8] = rb[it];        \
        }

    f32x4 acc[4][4] = {};

    LOAD_TILE(0)
    STORE_TILE()
    __syncthreads();

    for (int ks = 0; ks < KPAD / 32; ++ks) {
        if (ks + 1 < KPAD / 32) { LOAD_TILE((ks + 1) * 32) }  // prefetch (no wait)

        bf16x8 af[4], bfr[4];
        #pragma unroll
        for (int mt = 0; mt < 4; ++mt)
            af[mt] = *(const bf16x8*)&As[(m_off + mt * 16 + l16) * G1_STRIDE + quad * 8];
        #pragma unroll
        for (int nt = 0; nt < 4; ++nt)
            bfr[nt] = *(const bf16x8*)&Bs[(n_off + nt * 16 + l16) * G1_STRIDE + quad * 8];
        #pragma unroll
        for (int mt = 0; mt < 4; ++mt)
            #pragma unroll
            for (int nt = 0; nt < 4; ++nt)
                acc[mt][nt] = __builtin_amdgcn_mfma_f32_16x16x32_bf16(
                                  af[mt], bfr[nt], acc[mt][nt], 0, 0, 0);
        __syncthreads();                      // all waves done reading LDS
        if (ks + 1 < KPAD / 32) { STORE_TILE() }
        __syncthreads();
    }
    #undef LOAD_TILE
    #undef STORE_TILE

    // epilogue: bias + relu -> bf16; C/D layout col=lane&15, row=quad*4+reg
    #pragma unroll
    for (int nt = 0; nt < 4; ++nt) {
        int gc = n_off + nt * 16 + l16;
        float bb = bias[gc];
        #pragma unroll
        for (int mt = 0; mt < 4; ++mt) {
            #pragma unroll
            for (int r = 0; r < 4; ++r) {
                int gm = row0 + m_off + mt * 16 + quad * 4 + r;
                if (gm < M) {
                    float v = acc[mt][nt][r] + bb;
                    C[(size_t)gm * HID + gc] = f2bf(v > 0.f ? v : 0.f);
                }
            }
        }
    }
}

// ---------------------------------------------------------------------------
// GEMM2 (MFMA) + gate epilogue:
//   x = hid(bf16) @ W2 + b2 ; hs0 = packed-bf16(x*nrm) ; out = sigmoid(x.s)*x
// block = 256 threads (4 waves); tile 128(M) x 64(N); K=256, BK=64
// ---------------------------------------------------------------------------
#define A2_STRIDE 72
#define B2_STRIDE 264
__global__ __launch_bounds__(256) void dagnn_mlp2_mfma(
        const short* __restrict__ hid, const short* __restrict__ W2t,
        const float* __restrict__ b2, const float* __restrict__ svec,
        const float* __restrict__ nrm,
        unsigned* __restrict__ hs0, float* __restrict__ out, int M) {
    __shared__ __align__(16) short As[128 * A2_STRIDE];
    __shared__ __align__(16) short Bs[CPAD * B2_STRIDE];

    const int tid  = threadIdx.x;
    const int lane = tid & 63;
    const int wid  = tid >> 6;              // 0..3
    const int l16  = lane & 15;
    const int quad = lane >> 4;
    const int m_off = wid * 32;
    const int row0  = blockIdx.x * 128;

    // stage all of W2t (64 x 256) into LDS once
    #pragma unroll
    for (int it = 0; it < 8; ++it) {
        int slot = tid + it * 256;          // 0..2047
        int n   = slot >> 5;                // 0..63
        int seg = slot & 31;                // 8 bf16 each
        bf16x8 b = *(const bf16x8*)(W2t + (size_t)n * HID + seg * 8);
        *(bf16x8*)&Bs[n * B2_STRIDE + seg * 8] = b;
    }

    f32x4 acc[2][4] = {};

    for (int ks = 0; ks < HID / 64; ++ks) {     // 4 iterations, BK=64
        const int k0 = ks * 64;
        #pragma unroll
        for (int it = 0; it < 4; ++it) {
            int slot = tid + it * 256;      // 0..1023
            int m   = slot >> 3;            // 0..127
            int seg = slot & 7;             // 8 bf16 each
            int gm  = row0 + m;
            bf16x8 v = {};
            if (gm < M) v = *(const bf16x8*)(hid + (size_t)gm * HID + k0 + seg * 8);
            *(bf16x8*)&As[m * A2_STRIDE + seg * 8] = v;
        }
        __syncthreads();

        #pragma unroll
        for (int ksub = 0; ksub < 2; ++ksub) {
            bf16x8 af[2], bfr[4];
            #pragma unroll
            for (int mt = 0; mt < 2; ++mt)
                af[mt] = *(const bf16x8*)&As[(m_off + mt * 16 + l16) * A2_STRIDE
                                             + ksub * 32 + quad * 8];
            #pragma unroll
            for (int nt = 0; nt < 4; ++nt)
                bfr[nt] = *(const bf16x8*)&Bs[(nt * 16 + l16) * B2_STRIDE
                                              + k0 + ksub * 32 + quad * 8];
            #pragma unroll
            for (int mt = 0; mt < 2; ++mt)
                #pragma unroll
                for (int nt = 0; nt < 4; ++nt)
                    acc[mt][nt] = __builtin_amdgcn_mfma_f32_16x16x32_bf16(
                                      af[mt], bfr[nt], acc[mt][nt], 0, 0, 0);
        }
        __syncthreads();
    }

    float b2v[4], ssv[4];
    #pragma unroll
    for (int nt = 0; nt < 4; ++nt) {
        int gc = nt * 16 + l16;
        b2v[nt] = (gc < NCLASS) ? b2[gc]   : 0.f;
        ssv[nt] = (gc < NCLASS) ? svec[gc] : 0.f;
    }
    #pragma unroll
    for (int mt = 0; mt < 2; ++mt) {
        #pragma unroll
        for (int r = 0; r < 4; ++r) {
            int gm = row0 + m_off + mt * 16 + quad * 4 + r;
            float xv[4], q = 0.f;
            #pragma unroll
            for (int nt = 0; nt < 4; ++nt) {
                xv[nt] = acc[mt][nt][r] + b2v[nt];
                q += xv[nt] * ssv[nt];
            }
            #pragma unroll
            for (int off = 1; off < 16; off <<= 1) q += __shfl_xor(q, off);
            float S = 1.f / (1.f + __expf(-q));
            float nd = (gm < M) ? nrm[gm] : 0.f;
            #pragma unroll
            for (int nt = 0; nt < 4; ++nt) {
                int gc = nt * 16 + l16;
                float hv = xv[nt] * nd;
                float hp = __shfl_xor(hv, 1);     // partner lane's value
                if (gm < M) {
                    if (!(l16 & 1))               // even lane packs (gc, gc+1)
                        hs0[(size_t)gm * 32 + nt * 8 + (l16 >> 1)] = packbf(hv, hp);
                    if (gc < NCLASS) out[(size_t)gm * NCLASS + gc] = S * xv[nt];
                }
            }
        }
    }
}

// ---------------------------------------------------------------------------
// propagation hop (packed bf16 rows, 128 B/node):
//   r[d]       = nrm[d] * sum_{s in N(d)} hs[s]       (fp32 accumulate)
//   hs_next[d] = packed-bf16(r * nrm[d])
//   out[d]    += sigmoid(r . s) * r
// one wave per dst row; half-wave per edge (2 edges per load instruction)
// ---------------------------------------------------------------------------
__global__ __launch_bounds__(256) void dagnn_prop4(
        const unsigned* __restrict__ hs, const float* __restrict__ nrm,
        const int* __restrict__ rowptr, const int* __restrict__ colidx,
        const float2* __restrict__ sgate, unsigned* __restrict__ hs_next,
        float* __restrict__ out, int M, int write_next) {
    const int lane = threadIdx.x & 63;
    const int wid  = threadIdx.x >> 6;
    const int d    = blockIdx.x * 4 + wid;
    if (d >= M) return;
    const int half = lane >> 5;         // which edge of the pair
    const int c    = lane & 31;         // channel-pair index (ch 2c, 2c+1)
    const int beg = rowptr[d], end = rowptr[d + 1];

    float a0 = 0.f, a1 = 0.f;
    int e = beg;
    for (; e + 8 <= end; e += 8) {
        int s0 = colidx[e + half + 0];
        int s1 = colidx[e + half + 2];
        int s2 = colidx[e + half + 4];
        int s3 = colidx[e + half + 6];
        unsigned u0 = hs[(size_t)s0 * 32 + c];
        unsigned u1 = hs[(size_t)s1 * 32 + c];
        unsigned u2 = hs[(size_t)s2 * 32 + c];
        unsigned u3 = hs[(size_t)s3 * 32 + c];
        a0 += (bflo(u0) + bflo(u1)) + (bflo(u2) + bflo(u3));
        a1 += (bfhi(u0) + bfhi(u1)) + (bfhi(u2) + bfhi(u3));
    }
    for (; e + 2 <= end; e += 2) {
        int s = colidx[e + half];
        unsigned u = hs[(size_t)s * 32 + c];
        a0 += bflo(u); a1 += bfhi(u);
    }
    if (e < end && half == 0) {
        int s = colidx[e];
        unsigned u = hs[(size_t)s * 32 + c];
        a0 += bflo(u); a1 += bfhi(u);
    }
    a0 += __shfl_xor(a0, 32);           // combine the two half-wave partials
    a1 += __shfl_xor(a1, 32);

    float nd = nrm[d];
    float r0 = a0 * nd, r1 = a1 * nd;
    float2 g = sgate[c];
    float p = r0 * g.x + r1 * g.y;
    #pragma unroll
    for (int off = 16; off; off >>= 1) p += __shfl_xor(p, off);  // 32-lane sum
    float S = 1.f / (1.f + __expf(-p));
    if (half == 0) {
        if (write_next) hs_next[(size_t)d * 32 + c] = packbf(r0 * nd, r1 * nd);
        int ch = 2 * c;
        if (ch < NCLASS) {
            out[(size_t)d * NCLASS + ch]     += S * r0;
            out[(size_t)d * NCLASS + ch + 1] += S * r1;
        }
    }
}

// ---------------------------------------------------------------------------
extern "C" void kernel_launch(void* const* d_in, const int* in_sizes, int n_in,
                              void* d_out, int out_size, void* d_ws, size_t ws_size,
                              hipStream_t stream) {
    const float* feats = (const float*)d_in[0];
    const float* W1    = (const float*)d_in[1];
    const float* b1    = (const float*)d_in[2];
    const float* W2    = (const float*)d_in[3];
    const float* b2    = (const float*)d_in[4];
    const float* svec  = (const float*)d_in[5];
    const int*   src   = (const int*)d_in[6];
    const int*   dst   = (const int*)d_in[7];
    float* out = (float*)d_out;

    const int M = in_sizes[0] / INDIM;    // 100000
    const int E = in_sizes[6];            // 1600000

    // workspace carve-up
    char* p = (char*)d_ws;
    size_t off = 0;
    short*    hid   = (short*)   (p + off); off += roundup256((size_t)M * HID * 2);
    unsigned* hsA   = (unsigned*)(p + off); off += roundup256((size_t)M * 32 * 4);
    unsigned* hsB   = (unsigned*)(p + off); off += roundup256((size_t)M * 32 * 4);
    short*    W1t   = (short*)   (p + off); off += roundup256((size_t)HID * KPAD * 2);
    short*    W2t   = (short*)   (p + off); off += roundup256((size_t)CPAD * HID * 2);
    float2*   sgate = (float2*)  (p + off); off += roundup256(32 * sizeof(float2));
    int*      degi  = (int*)     (p + off); off += roundup256((size_t)M * 4);
    float*    nrm   = (float*)   (p + off); off += roundup256((size_t)M * 4);
    int*      rowptr= (int*)     (p + off); off += roundup256((size_t)(M + 1) * 4);
    int*      fillc = (int*)     (p + off); off += roundup256((size_t)M * 4);
    int*      colidx= (int*)     (p + off); off += roundup256((size_t)E * 4);
    (void)ws_size;

    // --- graph/degree prep ---
    dagnn_zero2<<<(M + 255) / 256, 256, 0, stream>>>(degi, fillc, M);
    dagnn_deg<<<(E + 255) / 256, 256, 0, stream>>>(dst, degi, E);
    dagnn_norm<<<(M + 255) / 256, 256, 0, stream>>>(degi, nrm, M);
    dagnn_scan<<<1, 1024, 0, stream>>>(degi, rowptr, M);
    dagnn_fill<<<(E + 255) / 256, 256, 0, stream>>>(src, dst, rowptr, fillc, colidx, E);

    // --- weight prep ---
    dagnn_w1t<<<(HID * KPAD + 255) / 256, 256, 0, stream>>>(W1, W1t);
    dagnn_w2t<<<(CPAD * HID + 255) / 256, 256, 0, stream>>>(W2, W2t);
    dagnn_sgate<<<1, 32, 0, stream>>>(svec, sgate);

    // --- MLP ---
    dagnn_gemm1_mfma<<<(M + 127) / 128, 512, 0, stream>>>(feats, W1t, b1, hid, M);
    dagnn_mlp2_mfma<<<(M + 127) / 128, 256, 0, stream>>>(hid, W2t, b2, svec, nrm,
                                                         hsA, out, M);

    // --- K propagation hops with online output accumulation ---
    unsigned* hin = hsA;
    unsigned* hout = hsB;
    for (int k = 0; k < KHOPS; ++k) {
        dagnn_prop4<<<(M + 3) / 4, 256, 0, stream>>>(hin, nrm, rowptr, colidx,
                                                     sgate, hout, out, M,
                                                     k < KHOPS - 1);
        unsigned* t = hin; hin = hout; hout = t;
    }
}